// Round 4
// baseline (848.725 us; speedup 1.0000x reference)
//
#include <hip/hip_runtime.h>
#include <stdint.h>

// HashGrid3D: L=16 levels, T=2^19 entries/level, F=2 features, trilinear.
// Latency-bound random gathers. R2/R3 lesson: the compiler (ISel + pressure-
// aware sched) always sinks its own loads next to their uses, capping MLP at
// ~8 loads/wave regardless of source order or sched_barrier fences.
// This version forces a depth-2 software pipeline with inline asm:
//   - buffer_load_dwordx2 via SRSRC (32-bit voffset, 1 addr VGPR per load)
//   - 8 batches x 2 levels = 16 loads/batch; batch k+1 issued before batch k
//     is consumed; hand-counted s_waitcnt vmcnt(16) (never 0 in steady state)
//   - volatile asm cannot be sunk; SIInsertWaitcnts can't see the loads, so
//     no auto vmcnt(0) drains appear
//   - "memory" clobber on each wait pins the output stores so the vmcnt
//     arithmetic stays conservative-correct; sched_barrier(0) after each wait
//     stops reg-only consume VALU from hoisting above it (rule-18 hazard)
// ~32 outstanding loads/wave x 16 waves/CU (launch_bounds(256,4), <=128 VGPR)
// = ~512 outstanding/CU vs ~130 before.

constexpr int   LVL   = 16;
constexpr int   TBL   = 524288;          // 2^19
constexpr uint32_t TMASK = 0x7FFFFu;     // T-1
constexpr uint32_t P2 = 2654435761u;
constexpr uint32_t P3 = 805459861u;
// RES[l] = round(16 * (512/16)^(l/15))
constexpr int RESV[LVL] = {16, 20, 25, 32, 40, 51, 64, 81,
                           102, 128, 161, 203, 256, 323, 406, 512};

typedef float f32x2 __attribute__((ext_vector_type(2)));
typedef float f32x4 __attribute__((ext_vector_type(4)));
typedef int   i32x4 __attribute__((ext_vector_type(4)));

#define SB()  __builtin_amdgcn_sched_barrier(0)
#define W16() asm volatile("s_waitcnt vmcnt(16)" ::: "memory")
#define W0()  asm volatile("s_waitcnt vmcnt(0)"  ::: "memory")

__device__ __forceinline__ i32x4 make_srsrc(const void* p) {
    union { struct { const void* p; uint32_t num; uint32_t fl; } s; i32x4 v; } u;
    u.s.p   = p;
    u.s.num = 0xFFFFFFFFu;       // disable bounds check
    u.s.fl  = 0x00020000u;       // raw untyped dword access
    return u.v;
}

// Issue 2 levels (16 buffer_load_dwordx2) via volatile asm; fills fr[6].
template<int L0>
__device__ __forceinline__ void issue2(i32x4 srsrc, float x, float y, float z,
                                       f32x2 (&g)[16], float (&fr)[6])
{
    #pragma unroll
    for (int j = 0; j < 2; ++j) {
        const int l = L0 + j;                 // compile-time
        const int N = RESV[l];
        const uint32_t base = (uint32_t)l * 4194304u;   // l * T * 8B

        float sx = x * (float)N, sy = y * (float)N, sz = z * (float)N;
        float fx = floorf(sx), fy = floorf(sy), fz = floorf(sz);
        fr[3*j+0] = sx - fx; fr[3*j+1] = sy - fy; fr[3*j+2] = sz - fz;
        int ix = (int)fx, iy = (int)fy, iz = (int)fz;

        // reference wraps every corner with % N; i0 can hit N on fp edge
        int ix0 = (ix >= N) ? ix - N : ix;
        int iy0 = (iy >= N) ? iy - N : iy;
        int iz0 = (iz >= N) ? iz - N : iz;
        int ix1 = ix + 1; ix1 = (ix1 >= N) ? ix1 - N : ix1;
        int iy1 = iy + 1; iy1 = (iy1 >= N) ? iy1 - N : iy1;
        int iz1 = iz + 1; iz1 = (iz1 >= N) ? iz1 - N : iz1;

        uint32_t hx0 = (uint32_t)ix0;          // prime 1
        uint32_t hx1 = (uint32_t)ix1;
        uint32_t hy0 = (uint32_t)iy0 * P2;
        uint32_t hy1 = (uint32_t)iy1 * P2;
        uint32_t hz0 = (uint32_t)iz0 * P3;
        uint32_t hz1 = (uint32_t)iz1 * P3;

        uint32_t o0 = base + (((hx0 ^ hy0 ^ hz0) & TMASK) << 3);
        uint32_t o1 = base + (((hx1 ^ hy0 ^ hz0) & TMASK) << 3);
        uint32_t o2 = base + (((hx0 ^ hy1 ^ hz0) & TMASK) << 3);
        uint32_t o3 = base + (((hx1 ^ hy1 ^ hz0) & TMASK) << 3);
        uint32_t o4 = base + (((hx0 ^ hy0 ^ hz1) & TMASK) << 3);
        uint32_t o5 = base + (((hx1 ^ hy0 ^ hz1) & TMASK) << 3);
        uint32_t o6 = base + (((hx0 ^ hy1 ^ hz1) & TMASK) << 3);
        uint32_t o7 = base + (((hx1 ^ hy1 ^ hz1) & TMASK) << 3);

        #define LD(dst, voff) \
            asm volatile("buffer_load_dwordx2 %0, %1, %2, 0 offen" \
                         : "=v"(dst) : "v"(voff), "s"(srsrc))
        LD(g[8*j+0], o0); LD(g[8*j+1], o1);
        LD(g[8*j+2], o2); LD(g[8*j+3], o3);
        LD(g[8*j+4], o4); LD(g[8*j+5], o5);
        LD(g[8*j+6], o6); LD(g[8*j+7], o7);
        #undef LD
    }
}

// Consume 2 levels -> 4 output floats (one dwordx4 store, L2-merged).
__device__ __forceinline__ void consume2(const f32x2 (&g)[16],
                                         const float (&fr)[6],
                                         float* __restrict__ o)
{
    float r[4];
    #pragma unroll
    for (int j = 0; j < 2; ++j) {
        float tx = fr[3*j+0], ty = fr[3*j+1], tz = fr[3*j+2];
        float wx1 = tx, wx0 = 1.0f - tx;
        float wy1 = ty, wy0 = 1.0f - ty;
        float wz1 = tz, wz0 = 1.0f - tz;
        float wz0y0 = wy0 * wz0, wz0y1 = wy1 * wz0;
        float wz1y0 = wy0 * wz1, wz1y1 = wy1 * wz1;
        float w0 = wx0 * wz0y0, w1 = wx1 * wz0y0;
        float w2 = wx0 * wz0y1, w3 = wx1 * wz0y1;
        float w4 = wx0 * wz1y0, w5 = wx1 * wz1y0;
        float w6 = wx0 * wz1y1, w7 = wx1 * wz1y1;

        r[2*j+0] = w0*g[8*j+0].x + w1*g[8*j+1].x + w2*g[8*j+2].x + w3*g[8*j+3].x
                 + w4*g[8*j+4].x + w5*g[8*j+5].x + w6*g[8*j+6].x + w7*g[8*j+7].x;
        r[2*j+1] = w0*g[8*j+0].y + w1*g[8*j+1].y + w2*g[8*j+2].y + w3*g[8*j+3].y
                 + w4*g[8*j+4].y + w5*g[8*j+5].y + w6*g[8*j+6].y + w7*g[8*j+7].y;
    }
    f32x4 v = { r[0], r[1], r[2], r[3] };
    *(f32x4*)o = v;
}

__global__ __launch_bounds__(256, 4)
void hashgrid3d_kernel(const float* __restrict__ xyt,
                       const float* __restrict__ tables,
                       float* __restrict__ out, int n)
{
    int p = blockIdx.x * 256 + threadIdx.x;
    if (p >= n) return;

    float x = xyt[3 * p + 0];
    float y = xyt[3 * p + 1];
    float z = xyt[3 * p + 2];

    i32x4 srsrc = make_srsrc(tables);
    float* o = out + (size_t)p * 32;

    f32x2 gA[16], gB[16];
    float frA[6], frB[6];

    // depth-2 pipeline: batch k+1's 16 loads always in flight while batch k
    // is consumed. vmcnt(16) == "16 newer VMEM ops may remain outstanding".
    issue2<0>(srsrc, x, y, z, gA, frA);
    issue2<2>(srsrc, x, y, z, gB, frB);
    W16(); SB();
    consume2(gA, frA, o + 0);
    issue2<4>(srsrc, x, y, z, gA, frA);
    W16(); SB();
    consume2(gB, frB, o + 4);
    issue2<6>(srsrc, x, y, z, gB, frB);
    W16(); SB();
    consume2(gA, frA, o + 8);
    issue2<8>(srsrc, x, y, z, gA, frA);
    W16(); SB();
    consume2(gB, frB, o + 12);
    issue2<10>(srsrc, x, y, z, gB, frB);
    W16(); SB();
    consume2(gA, frA, o + 16);
    issue2<12>(srsrc, x, y, z, gA, frA);
    W16(); SB();
    consume2(gB, frB, o + 20);
    issue2<14>(srsrc, x, y, z, gB, frB);
    W16(); SB();
    consume2(gA, frA, o + 24);
    W0(); SB();
    consume2(gB, frB, o + 28);
}

extern "C" void kernel_launch(void* const* d_in, const int* in_sizes, int n_in,
                              void* d_out, int out_size, void* d_ws, size_t ws_size,
                              hipStream_t stream) {
    const float* xyt    = (const float*)d_in[0];   // (1048576, 3) f32
    const float* tables = (const float*)d_in[1];   // (16, 524288, 2) f32
    float* out = (float*)d_out;                    // (1048576, 32) f32
    int n = in_sizes[0] / 3;
    int blocks = (n + 255) / 256;
    hashgrid3d_kernel<<<blocks, 256, 0, stream>>>(xyt, tables, out, n);
}

// Round 5
// 826.438 us; speedup vs baseline: 1.0270x; 1.0270x over previous
//
#include <hip/hip_runtime.h>
#include <stdint.h>

// HashGrid3D: L=16 levels, T=2^19 entries/level, F=2 features, trilinear.
//
// R2-R4 lesson: dur_us is invariant (~685-725us) across occupancy 41-72%,
// VGPR 32-52, compiler and hand-asm schedules => NOT per-wave-MLP bound.
// The per-CU miss path saturates at ~0.32 line-requests/cy/CU at every
// tested config: the binding resource is the NUMBER of distinct-cache-line
// requests (128 hash gathers/point, each its own line).
//
// Fix: pre-densify levels 0..7 (N=16..81) into dense [z][y][x] arrays in the
// workspace, x-row padded with one wrap entry so the (x0,x0+1) corner pair is
// always 8B-adjacent:
//   - pair's 2nd load MSHR-merges / L1-hits instead of a 2nd miss-queue entry
//     (8 -> ~4.5 line requests per dense level per point)
//   - levels 0..5 dense = 2.1 MB total -> near-always L2 hits (hash scatter
//     had inflated their L2 footprint ~4x), freeing L2 for the big levels.
// Levels 8..15 keep the original hash gathers.
// Build kernel: 1.07M one-time gathers (~1% of main kernel's), every launch.
// Host falls back to the proven R1 kernel if ws_size < 8.6 MB.

constexpr int   LVL   = 16;
constexpr int   TBL   = 524288;          // 2^19
constexpr uint32_t TMASK = 0x7FFFFu;     // T-1
constexpr uint32_t P2 = 2654435761u;
constexpr uint32_t P3 = 805459861u;
// RES[l] = round(16 * (512/16)^(l/15))
constexpr int RESV[LVL] = {16, 20, 25, 32, 40, 51, 64, 81,
                           102, 128, 161, 203, 256, 323, 406, 512};

constexpr int NDL = 8;                   // levels 0..7 densified
// OFFE[l+1] = OFFE[l] + N^2*(N+1), N = RESV[l]  (entries are float2)
constexpr int OFFE[NDL + 1] = {0, 4352, 12752, 29002, 62794,
                               128394, 263646, 529886, 1067888};
constexpr size_t DENSE_BYTES = (size_t)1067888 * 8;   // 8,543,104 B

// ---------------- build kernel: hash table -> dense [z][y][x+pad] ----------
__global__ __launch_bounds__(256)
void build_dense(const float* __restrict__ tables, float2* __restrict__ dws)
{
    int tid = blockIdx.x * 256 + threadIdx.x;
    if (tid >= OFFE[NDL]) return;
    const float2* t2 = (const float2*)tables;
    #pragma unroll
    for (int l = 0; l < NDL; ++l) {
        if (tid < OFFE[l + 1]) {
            const int N = RESV[l], R = N + 1;      // compile-time per branch
            int idx = tid - OFFE[l];
            int xx = idx % R;                      // magic-mul (constexpr R)
            int q  = idx / R;
            int yy = q % N;
            int zz = q / N;
            uint32_t xw = (xx == N) ? 0u : (uint32_t)xx;   // pad col = col 0
            uint32_t h = (xw ^ ((uint32_t)yy * P2) ^ ((uint32_t)zz * P3)) & TMASK;
            dws[tid] = t2[(size_t)l * TBL + h];
            return;
        }
    }
}

// ---------------- shared per-level interpolation helpers -------------------
__device__ __forceinline__ void trilerp(float tx, float ty, float tz,
                                        float2 g000, float2 g100, float2 g010, float2 g110,
                                        float2 g001, float2 g101, float2 g011, float2 g111,
                                        float* __restrict__ o)
{
    float wx1 = tx, wx0 = 1.0f - tx;
    float wy1 = ty, wy0 = 1.0f - ty;
    float wz1 = tz, wz0 = 1.0f - tz;
    float wz0y0 = wy0 * wz0, wz0y1 = wy1 * wz0;
    float wz1y0 = wy0 * wz1, wz1y1 = wy1 * wz1;
    float w000 = wx0 * wz0y0, w100 = wx1 * wz0y0;
    float w010 = wx0 * wz0y1, w110 = wx1 * wz0y1;
    float w001 = wx0 * wz1y0, w101 = wx1 * wz1y0;
    float w011 = wx0 * wz1y1, w111 = wx1 * wz1y1;
    o[0] = w000*g000.x + w100*g100.x + w010*g010.x + w110*g110.x
         + w001*g001.x + w101*g101.x + w011*g011.x + w111*g111.x;
    o[1] = w000*g000.y + w100*g100.y + w010*g010.y + w110*g110.y
         + w001*g001.y + w101*g101.y + w011*g011.y + w111*g111.y;
}

// ---------------- main kernel: dense levels 0..7, hash levels 8..15 --------
__global__ __launch_bounds__(256)
void hashgrid3d_dense(const float* __restrict__ xyt,
                      const float* __restrict__ tables,
                      const float2* __restrict__ dense,
                      float* __restrict__ out, int n)
{
    int p = blockIdx.x * 256 + threadIdx.x;
    if (p >= n) return;

    float x = xyt[3 * p + 0];
    float y = xyt[3 * p + 1];
    float z = xyt[3 * p + 2];

    float outv[2 * LVL];

    // dense levels: x-pair is 8B-adjacent (padded wrap column)
    #pragma unroll
    for (int l = 0; l < NDL; ++l) {
        const int N = RESV[l], R = N + 1;
        const float2* __restrict__ dl = dense + OFFE[l];

        float sx = x * (float)N, sy = y * (float)N, sz = z * (float)N;
        float fx = floorf(sx), fy = floorf(sy), fz = floorf(sz);
        float tx = sx - fx, ty = sy - fy, tz = sz - fz;
        int ix = (int)fx, iy = (int)fy, iz = (int)fz;

        // wrap corner 0 (i0 can hit N on the fp rounding edge, ref does %N)
        int ix0 = (ix >= N) ? ix - N : ix;
        int iy0 = (iy >= N) ? iy - N : iy;
        int iz0 = (iz >= N) ? iz - N : iz;
        int iy1 = iy0 + 1; iy1 = (iy1 >= N) ? 0 : iy1;   // == (iy+1)%N
        int iz1 = iz0 + 1; iz1 = (iz1 >= N) ? 0 : iz1;
        // x1 handled by the pad column: dl[b+1] with b at x=ix0 (ix0<=N-1)

        int b00 = (iz0 * N + iy0) * R + ix0;
        int b10 = (iz0 * N + iy1) * R + ix0;
        int b01 = (iz1 * N + iy0) * R + ix0;
        int b11 = (iz1 * N + iy1) * R + ix0;

        float2 g000 = dl[b00], g100 = dl[b00 + 1];
        float2 g010 = dl[b10], g110 = dl[b10 + 1];
        float2 g001 = dl[b01], g101 = dl[b01 + 1];
        float2 g011 = dl[b11], g111 = dl[b11 + 1];

        trilerp(tx, ty, tz, g000, g100, g010, g110, g001, g101, g011, g111,
                &outv[2 * l]);
    }

    // hash levels: original 8-gather path
    #pragma unroll
    for (int l = NDL; l < LVL; ++l) {
        const int N = RESV[l];
        const float2* __restrict__ tbl = (const float2*)tables + (size_t)l * TBL;

        float sx = x * (float)N, sy = y * (float)N, sz = z * (float)N;
        float fx = floorf(sx), fy = floorf(sy), fz = floorf(sz);
        float tx = sx - fx, ty = sy - fy, tz = sz - fz;
        int ix = (int)fx, iy = (int)fy, iz = (int)fz;

        int ix0 = (ix >= N) ? ix - N : ix;
        int iy0 = (iy >= N) ? iy - N : iy;
        int iz0 = (iz >= N) ? iz - N : iz;
        int ix1 = ix + 1; ix1 = (ix1 >= N) ? ix1 - N : ix1;
        int iy1 = iy + 1; iy1 = (iy1 >= N) ? iy1 - N : iy1;
        int iz1 = iz + 1; iz1 = (iz1 >= N) ? iz1 - N : iz1;

        uint32_t hx0 = (uint32_t)ix0;
        uint32_t hx1 = (uint32_t)ix1;
        uint32_t hy0 = (uint32_t)iy0 * P2;
        uint32_t hy1 = (uint32_t)iy1 * P2;
        uint32_t hz0 = (uint32_t)iz0 * P3;
        uint32_t hz1 = (uint32_t)iz1 * P3;

        float2 g000 = tbl[(hx0 ^ hy0 ^ hz0) & TMASK];
        float2 g100 = tbl[(hx1 ^ hy0 ^ hz0) & TMASK];
        float2 g010 = tbl[(hx0 ^ hy1 ^ hz0) & TMASK];
        float2 g110 = tbl[(hx1 ^ hy1 ^ hz0) & TMASK];
        float2 g001 = tbl[(hx0 ^ hy0 ^ hz1) & TMASK];
        float2 g101 = tbl[(hx1 ^ hy0 ^ hz1) & TMASK];
        float2 g011 = tbl[(hx0 ^ hy1 ^ hz1) & TMASK];
        float2 g111 = tbl[(hx1 ^ hy1 ^ hz1) & TMASK];

        trilerp(tx, ty, tz, g000, g100, g010, g110, g001, g101, g011, g111,
                &outv[2 * l]);
    }

    float4* o = (float4*)(out + (size_t)p * 32);
    #pragma unroll
    for (int i = 0; i < 8; ++i)
        o[i] = ((const float4*)outv)[i];
}

// ---------------- fallback: proven R1 kernel (all-hash) --------------------
__global__ __launch_bounds__(256)
void hashgrid3d_hash(const float* __restrict__ xyt,
                     const float* __restrict__ tables,
                     float* __restrict__ out, int n)
{
    int p = blockIdx.x * 256 + threadIdx.x;
    if (p >= n) return;

    float x = xyt[3 * p + 0];
    float y = xyt[3 * p + 1];
    float z = xyt[3 * p + 2];

    float outv[2 * LVL];

    #pragma unroll
    for (int l = 0; l < LVL; ++l) {
        const int N = RESV[l];
        const float2* __restrict__ tbl = (const float2*)tables + (size_t)l * TBL;

        float sx = x * (float)N, sy = y * (float)N, sz = z * (float)N;
        float fx = floorf(sx), fy = floorf(sy), fz = floorf(sz);
        float tx = sx - fx, ty = sy - fy, tz = sz - fz;
        int ix = (int)fx, iy = (int)fy, iz = (int)fz;

        int ix0 = (ix >= N) ? ix - N : ix;
        int iy0 = (iy >= N) ? iy - N : iy;
        int iz0 = (iz >= N) ? iz - N : iz;
        int ix1 = ix + 1; ix1 = (ix1 >= N) ? ix1 - N : ix1;
        int iy1 = iy + 1; iy1 = (iy1 >= N) ? iy1 - N : iy1;
        int iz1 = iz + 1; iz1 = (iz1 >= N) ? iz1 - N : iz1;

        uint32_t hx0 = (uint32_t)ix0;
        uint32_t hx1 = (uint32_t)ix1;
        uint32_t hy0 = (uint32_t)iy0 * P2;
        uint32_t hy1 = (uint32_t)iy1 * P2;
        uint32_t hz0 = (uint32_t)iz0 * P3;
        uint32_t hz1 = (uint32_t)iz1 * P3;

        float2 g000 = tbl[(hx0 ^ hy0 ^ hz0) & TMASK];
        float2 g100 = tbl[(hx1 ^ hy0 ^ hz0) & TMASK];
        float2 g010 = tbl[(hx0 ^ hy1 ^ hz0) & TMASK];
        float2 g110 = tbl[(hx1 ^ hy1 ^ hz0) & TMASK];
        float2 g001 = tbl[(hx0 ^ hy0 ^ hz1) & TMASK];
        float2 g101 = tbl[(hx1 ^ hy0 ^ hz1) & TMASK];
        float2 g011 = tbl[(hx0 ^ hy1 ^ hz1) & TMASK];
        float2 g111 = tbl[(hx1 ^ hy1 ^ hz1) & TMASK];

        trilerp(tx, ty, tz, g000, g100, g010, g110, g001, g101, g011, g111,
                &outv[2 * l]);
    }

    float4* o = (float4*)(out + (size_t)p * 32);
    #pragma unroll
    for (int i = 0; i < 8; ++i)
        o[i] = ((const float4*)outv)[i];
}

extern "C" void kernel_launch(void* const* d_in, const int* in_sizes, int n_in,
                              void* d_out, int out_size, void* d_ws, size_t ws_size,
                              hipStream_t stream) {
    const float* xyt    = (const float*)d_in[0];   // (1048576, 3) f32
    const float* tables = (const float*)d_in[1];   // (16, 524288, 2) f32
    float* out = (float*)d_out;                    // (1048576, 32) f32
    int n = in_sizes[0] / 3;
    int blocks = (n + 255) / 256;

    if (d_ws != nullptr && ws_size >= DENSE_BYTES) {
        int bblocks = (OFFE[NDL] + 255) / 256;
        build_dense<<<bblocks, 256, 0, stream>>>(tables, (float2*)d_ws);
        hashgrid3d_dense<<<blocks, 256, 0, stream>>>(xyt, tables,
                                                     (const float2*)d_ws, out, n);
    } else {
        hashgrid3d_hash<<<blocks, 256, 0, stream>>>(xyt, tables, out, n);
    }
}

// Round 6
// 604.277 us; speedup vs baseline: 1.4045x; 1.3676x over previous
//
#include <hip/hip_runtime.h>
#include <stdint.h>

// HashGrid3D: L=16 levels, T=2^19 entries/level, F=2 features, trilinear.
//
// Evidence through R5: time is insensitive to occupancy (41-72%), VGPR
// (32-52), schedule (compiler vs hand-asm pipeline), and only weakly to
// L1->L2 request count (-25% requests -> -8.5% time). The stable cost term
// is L2-MISS traffic: ~30 lines/point fetched from fabric/L3 at ~48G
// random-64B-lines/s. Levels 8-15 (8 x 4MB hash tables, 32MB hot) miss L2
// because each XCD's 4MB L2 replicates a random 1/8 of that set.
//
// Fix: temporal partitioning. One pass per hash level 8..15: all CUs touch
// ONLY that level's 4MB table -> fits each XCD's L2 -> compulsory misses
// only. Pass results go to compact SoA buffers in ws (nontemporal stores,
// coalesced). Final kernel: dense levels 0-7 (R5 scheme, small working set)
// + coalesced SoA reads + 128B/point output assembly.
// ws layout: [0, 8.5MB) dense levels 0-7 | [8543232, +64MB) SoA f2[8][n].
// Fallbacks: ws too small -> R5 dense scheme -> R1 all-hash kernel.

constexpr int   LVL   = 16;
constexpr int   TBL   = 524288;          // 2^19
constexpr uint32_t TMASK = 0x7FFFFu;     // T-1
constexpr uint32_t P2 = 2654435761u;
constexpr uint32_t P3 = 805459861u;
// RES[l] = round(16 * (512/16)^(l/15))
constexpr int RESV[LVL] = {16, 20, 25, 32, 40, 51, 64, 81,
                           102, 128, 161, 203, 256, 323, 406, 512};

constexpr int NDL = 8;                   // levels 0..7 densified
// OFFE[l+1] = OFFE[l] + N^2*(N+1), N = RESV[l]  (entries are float2)
constexpr int OFFE[NDL + 1] = {0, 4352, 12752, 29002, 62794,
                               128394, 263646, 529886, 1067888};
constexpr size_t DENSE_BYTES = (size_t)1067888 * 8;   // 8,543,104 B
constexpr size_t SOA_OFF     = 8543232;               // 256B-aligned

typedef float f32x2 __attribute__((ext_vector_type(2)));

// ---------------- build kernel: hash table -> dense [z][y][x+pad] ----------
__global__ __launch_bounds__(256)
void build_dense(const float* __restrict__ tables, float2* __restrict__ dws)
{
    int tid = blockIdx.x * 256 + threadIdx.x;
    if (tid >= OFFE[NDL]) return;
    const float2* t2 = (const float2*)tables;
    #pragma unroll
    for (int l = 0; l < NDL; ++l) {
        if (tid < OFFE[l + 1]) {
            const int N = RESV[l], R = N + 1;      // compile-time per branch
            int idx = tid - OFFE[l];
            int xx = idx % R;
            int q  = idx / R;
            int yy = q % N;
            int zz = q / N;
            uint32_t xw = (xx == N) ? 0u : (uint32_t)xx;   // pad col = col 0
            uint32_t h = (xw ^ ((uint32_t)yy * P2) ^ ((uint32_t)zz * P3)) & TMASK;
            dws[tid] = t2[(size_t)l * TBL + h];
            return;
        }
    }
}

// ---------------- shared trilinear helper ----------------------------------
__device__ __forceinline__ void trilerp(float tx, float ty, float tz,
                                        float2 g000, float2 g100, float2 g010, float2 g110,
                                        float2 g001, float2 g101, float2 g011, float2 g111,
                                        float* __restrict__ o)
{
    float wx1 = tx, wx0 = 1.0f - tx;
    float wy1 = ty, wy0 = 1.0f - ty;
    float wz1 = tz, wz0 = 1.0f - tz;
    float wz0y0 = wy0 * wz0, wz0y1 = wy1 * wz0;
    float wz1y0 = wy0 * wz1, wz1y1 = wy1 * wz1;
    float w000 = wx0 * wz0y0, w100 = wx1 * wz0y0;
    float w010 = wx0 * wz0y1, w110 = wx1 * wz0y1;
    float w001 = wx0 * wz1y0, w101 = wx1 * wz1y0;
    float w011 = wx0 * wz1y1, w111 = wx1 * wz1y1;
    o[0] = w000*g000.x + w100*g100.x + w010*g010.x + w110*g110.x
         + w001*g001.x + w101*g101.x + w011*g011.x + w111*g111.x;
    o[1] = w000*g000.y + w100*g100.y + w010*g010.y + w110*g110.y
         + w001*g001.y + w101*g101.y + w011*g011.y + w111*g111.y;
}

// ---------------- per-level pass: one 4MB table, L2-resident per XCD -------
template<int LH>
__global__ __launch_bounds__(256)
void pass_hash(const float* __restrict__ xyt,
               const float* __restrict__ tables,
               float* __restrict__ soa, int n)   // soa = this level's slice
{
    int p = blockIdx.x * 256 + threadIdx.x;
    if (p >= n) return;

    // streaming reads: nt hint keeps them from evicting the resident table
    float x = __builtin_nontemporal_load(xyt + 3 * p + 0);
    float y = __builtin_nontemporal_load(xyt + 3 * p + 1);
    float z = __builtin_nontemporal_load(xyt + 3 * p + 2);

    const int N = RESV[LH];
    const float2* __restrict__ tbl = (const float2*)tables + (size_t)LH * TBL;

    float sx = x * (float)N, sy = y * (float)N, sz = z * (float)N;
    float fx = floorf(sx), fy = floorf(sy), fz = floorf(sz);
    float tx = sx - fx, ty = sy - fy, tz = sz - fz;
    int ix = (int)fx, iy = (int)fy, iz = (int)fz;

    int ix0 = (ix >= N) ? ix - N : ix;
    int iy0 = (iy >= N) ? iy - N : iy;
    int iz0 = (iz >= N) ? iz - N : iz;
    int ix1 = ix + 1; ix1 = (ix1 >= N) ? ix1 - N : ix1;
    int iy1 = iy + 1; iy1 = (iy1 >= N) ? iy1 - N : iy1;
    int iz1 = iz + 1; iz1 = (iz1 >= N) ? iz1 - N : iz1;

    uint32_t hx0 = (uint32_t)ix0;
    uint32_t hx1 = (uint32_t)ix1;
    uint32_t hy0 = (uint32_t)iy0 * P2;
    uint32_t hy1 = (uint32_t)iy1 * P2;
    uint32_t hz0 = (uint32_t)iz0 * P3;
    uint32_t hz1 = (uint32_t)iz1 * P3;

    float2 g000 = tbl[(hx0 ^ hy0 ^ hz0) & TMASK];
    float2 g100 = tbl[(hx1 ^ hy0 ^ hz0) & TMASK];
    float2 g010 = tbl[(hx0 ^ hy1 ^ hz0) & TMASK];
    float2 g110 = tbl[(hx1 ^ hy1 ^ hz0) & TMASK];
    float2 g001 = tbl[(hx0 ^ hy0 ^ hz1) & TMASK];
    float2 g101 = tbl[(hx1 ^ hy0 ^ hz1) & TMASK];
    float2 g011 = tbl[(hx0 ^ hy1 ^ hz1) & TMASK];
    float2 g111 = tbl[(hx1 ^ hy1 ^ hz1) & TMASK];

    float r[2];
    trilerp(tx, ty, tz, g000, g100, g010, g110, g001, g101, g011, g111, r);
    f32x2 v = { r[0], r[1] };
    __builtin_nontemporal_store(v, (f32x2*)(soa + 2 * (size_t)p));
}

// ---------------- final: dense levels 0-7 + SoA assembly -------------------
__global__ __launch_bounds__(256)
void final_assemble(const float* __restrict__ xyt,
                    const float2* __restrict__ dense,
                    const float* __restrict__ soa,   // f2[8][n]
                    float* __restrict__ out, int n)
{
    int p = blockIdx.x * 256 + threadIdx.x;
    if (p >= n) return;

    float x = xyt[3 * p + 0];
    float y = xyt[3 * p + 1];
    float z = xyt[3 * p + 2];

    float outv[2 * LVL];

    #pragma unroll
    for (int l = 0; l < NDL; ++l) {
        const int N = RESV[l], R = N + 1;
        const float2* __restrict__ dl = dense + OFFE[l];

        float sx = x * (float)N, sy = y * (float)N, sz = z * (float)N;
        float fx = floorf(sx), fy = floorf(sy), fz = floorf(sz);
        float tx = sx - fx, ty = sy - fy, tz = sz - fz;
        int ix = (int)fx, iy = (int)fy, iz = (int)fz;

        int ix0 = (ix >= N) ? ix - N : ix;
        int iy0 = (iy >= N) ? iy - N : iy;
        int iz0 = (iz >= N) ? iz - N : iz;
        int iy1 = iy0 + 1; iy1 = (iy1 >= N) ? 0 : iy1;
        int iz1 = iz0 + 1; iz1 = (iz1 >= N) ? 0 : iz1;

        int b00 = (iz0 * N + iy0) * R + ix0;
        int b10 = (iz0 * N + iy1) * R + ix0;
        int b01 = (iz1 * N + iy0) * R + ix0;
        int b11 = (iz1 * N + iy1) * R + ix0;

        float2 g000 = dl[b00], g100 = dl[b00 + 1];
        float2 g010 = dl[b10], g110 = dl[b10 + 1];
        float2 g001 = dl[b01], g101 = dl[b01 + 1];
        float2 g011 = dl[b11], g111 = dl[b11 + 1];

        trilerp(tx, ty, tz, g000, g100, g010, g110, g001, g101, g011, g111,
                &outv[2 * l]);
    }

    #pragma unroll
    for (int l = 0; l < 8; ++l) {
        f32x2 v = __builtin_nontemporal_load(
            (const f32x2*)(soa + 2 * ((size_t)l * (size_t)n + (size_t)p)));
        outv[2 * (NDL + l) + 0] = v.x;
        outv[2 * (NDL + l) + 1] = v.y;
    }

    float4* o = (float4*)(out + (size_t)p * 32);
    #pragma unroll
    for (int i = 0; i < 8; ++i)
        o[i] = ((const float4*)outv)[i];
}

// ---------------- fallback B: R5 dense+hash single kernel ------------------
__global__ __launch_bounds__(256)
void hashgrid3d_dense(const float* __restrict__ xyt,
                      const float* __restrict__ tables,
                      const float2* __restrict__ dense,
                      float* __restrict__ out, int n)
{
    int p = blockIdx.x * 256 + threadIdx.x;
    if (p >= n) return;

    float x = xyt[3 * p + 0];
    float y = xyt[3 * p + 1];
    float z = xyt[3 * p + 2];

    float outv[2 * LVL];

    #pragma unroll
    for (int l = 0; l < NDL; ++l) {
        const int N = RESV[l], R = N + 1;
        const float2* __restrict__ dl = dense + OFFE[l];

        float sx = x * (float)N, sy = y * (float)N, sz = z * (float)N;
        float fx = floorf(sx), fy = floorf(sy), fz = floorf(sz);
        float tx = sx - fx, ty = sy - fy, tz = sz - fz;
        int ix = (int)fx, iy = (int)fy, iz = (int)fz;

        int ix0 = (ix >= N) ? ix - N : ix;
        int iy0 = (iy >= N) ? iy - N : iy;
        int iz0 = (iz >= N) ? iz - N : iz;
        int iy1 = iy0 + 1; iy1 = (iy1 >= N) ? 0 : iy1;
        int iz1 = iz0 + 1; iz1 = (iz1 >= N) ? 0 : iz1;

        int b00 = (iz0 * N + iy0) * R + ix0;
        int b10 = (iz0 * N + iy1) * R + ix0;
        int b01 = (iz1 * N + iy0) * R + ix0;
        int b11 = (iz1 * N + iy1) * R + ix0;

        float2 g000 = dl[b00], g100 = dl[b00 + 1];
        float2 g010 = dl[b10], g110 = dl[b10 + 1];
        float2 g001 = dl[b01], g101 = dl[b01 + 1];
        float2 g011 = dl[b11], g111 = dl[b11 + 1];

        trilerp(tx, ty, tz, g000, g100, g010, g110, g001, g101, g011, g111,
                &outv[2 * l]);
    }

    #pragma unroll
    for (int l = NDL; l < LVL; ++l) {
        const int N = RESV[l];
        const float2* __restrict__ tbl = (const float2*)tables + (size_t)l * TBL;

        float sx = x * (float)N, sy = y * (float)N, sz = z * (float)N;
        float fx = floorf(sx), fy = floorf(sy), fz = floorf(sz);
        float tx = sx - fx, ty = sy - fy, tz = sz - fz;
        int ix = (int)fx, iy = (int)fy, iz = (int)fz;

        int ix0 = (ix >= N) ? ix - N : ix;
        int iy0 = (iy >= N) ? iy - N : iy;
        int iz0 = (iz >= N) ? iz - N : iz;
        int ix1 = ix + 1; ix1 = (ix1 >= N) ? ix1 - N : ix1;
        int iy1 = iy + 1; iy1 = (iy1 >= N) ? iy1 - N : iy1;
        int iz1 = iz + 1; iz1 = (iz1 >= N) ? iz1 - N : iz1;

        uint32_t hx0 = (uint32_t)ix0;
        uint32_t hx1 = (uint32_t)ix1;
        uint32_t hy0 = (uint32_t)iy0 * P2;
        uint32_t hy1 = (uint32_t)iy1 * P2;
        uint32_t hz0 = (uint32_t)iz0 * P3;
        uint32_t hz1 = (uint32_t)iz1 * P3;

        float2 g000 = tbl[(hx0 ^ hy0 ^ hz0) & TMASK];
        float2 g100 = tbl[(hx1 ^ hy0 ^ hz0) & TMASK];
        float2 g010 = tbl[(hx0 ^ hy1 ^ hz0) & TMASK];
        float2 g110 = tbl[(hx1 ^ hy1 ^ hz0) & TMASK];
        float2 g001 = tbl[(hx0 ^ hy0 ^ hz1) & TMASK];
        float2 g101 = tbl[(hx1 ^ hy0 ^ hz1) & TMASK];
        float2 g011 = tbl[(hx0 ^ hy1 ^ hz1) & TMASK];
        float2 g111 = tbl[(hx1 ^ hy1 ^ hz1) & TMASK];

        trilerp(tx, ty, tz, g000, g100, g010, g110, g001, g101, g011, g111,
                &outv[2 * l]);
    }

    float4* o = (float4*)(out + (size_t)p * 32);
    #pragma unroll
    for (int i = 0; i < 8; ++i)
        o[i] = ((const float4*)outv)[i];
}

// ---------------- fallback C: R1 all-hash kernel ---------------------------
__global__ __launch_bounds__(256)
void hashgrid3d_hash(const float* __restrict__ xyt,
                     const float* __restrict__ tables,
                     float* __restrict__ out, int n)
{
    int p = blockIdx.x * 256 + threadIdx.x;
    if (p >= n) return;

    float x = xyt[3 * p + 0];
    float y = xyt[3 * p + 1];
    float z = xyt[3 * p + 2];

    float outv[2 * LVL];

    #pragma unroll
    for (int l = 0; l < LVL; ++l) {
        const int N = RESV[l];
        const float2* __restrict__ tbl = (const float2*)tables + (size_t)l * TBL;

        float sx = x * (float)N, sy = y * (float)N, sz = z * (float)N;
        float fx = floorf(sx), fy = floorf(sy), fz = floorf(sz);
        float tx = sx - fx, ty = sy - fy, tz = sz - fz;
        int ix = (int)fx, iy = (int)fy, iz = (int)fz;

        int ix0 = (ix >= N) ? ix - N : ix;
        int iy0 = (iy >= N) ? iy - N : iy;
        int iz0 = (iz >= N) ? iz - N : iz;
        int ix1 = ix + 1; ix1 = (ix1 >= N) ? ix1 - N : ix1;
        int iy1 = iy + 1; iy1 = (iy1 >= N) ? iy1 - N : iy1;
        int iz1 = iz + 1; iz1 = (iz1 >= N) ? iz1 - N : iz1;

        uint32_t hx0 = (uint32_t)ix0;
        uint32_t hx1 = (uint32_t)ix1;
        uint32_t hy0 = (uint32_t)iy0 * P2;
        uint32_t hy1 = (uint32_t)iy1 * P2;
        uint32_t hz0 = (uint32_t)iz0 * P3;
        uint32_t hz1 = (uint32_t)iz1 * P3;

        float2 g000 = tbl[(hx0 ^ hy0 ^ hz0) & TMASK];
        float2 g100 = tbl[(hx1 ^ hy0 ^ hz0) & TMASK];
        float2 g010 = tbl[(hx0 ^ hy1 ^ hz0) & TMASK];
        float2 g110 = tbl[(hx1 ^ hy1 ^ hz0) & TMASK];
        float2 g001 = tbl[(hx0 ^ hy0 ^ hz1) & TMASK];
        float2 g101 = tbl[(hx1 ^ hy0 ^ hz1) & TMASK];
        float2 g011 = tbl[(hx0 ^ hy1 ^ hz1) & TMASK];
        float2 g111 = tbl[(hx1 ^ hy1 ^ hz1) & TMASK];

        trilerp(tx, ty, tz, g000, g100, g010, g110, g001, g101, g011, g111,
                &outv[2 * l]);
    }

    float4* o = (float4*)(out + (size_t)p * 32);
    #pragma unroll
    for (int i = 0; i < 8; ++i)
        o[i] = ((const float4*)outv)[i];
}

extern "C" void kernel_launch(void* const* d_in, const int* in_sizes, int n_in,
                              void* d_out, int out_size, void* d_ws, size_t ws_size,
                              hipStream_t stream) {
    const float* xyt    = (const float*)d_in[0];   // (1048576, 3) f32
    const float* tables = (const float*)d_in[1];   // (16, 524288, 2) f32
    float* out = (float*)d_out;                    // (1048576, 32) f32
    int n = in_sizes[0] / 3;
    int blocks = (n + 255) / 256;

    size_t need_full = SOA_OFF + (size_t)64 * (size_t)n;   // dense + 8*n*8B

    if (d_ws != nullptr && ws_size >= need_full) {
        int bblocks = (OFFE[NDL] + 255) / 256;
        build_dense<<<bblocks, 256, 0, stream>>>(tables, (float2*)d_ws);

        float* soa = (float*)((char*)d_ws + SOA_OFF);
        size_t stride = 2 * (size_t)n;
        pass_hash< 8><<<blocks, 256, 0, stream>>>(xyt, tables, soa + 0 * stride, n);
        pass_hash< 9><<<blocks, 256, 0, stream>>>(xyt, tables, soa + 1 * stride, n);
        pass_hash<10><<<blocks, 256, 0, stream>>>(xyt, tables, soa + 2 * stride, n);
        pass_hash<11><<<blocks, 256, 0, stream>>>(xyt, tables, soa + 3 * stride, n);
        pass_hash<12><<<blocks, 256, 0, stream>>>(xyt, tables, soa + 4 * stride, n);
        pass_hash<13><<<blocks, 256, 0, stream>>>(xyt, tables, soa + 5 * stride, n);
        pass_hash<14><<<blocks, 256, 0, stream>>>(xyt, tables, soa + 6 * stride, n);
        pass_hash<15><<<blocks, 256, 0, stream>>>(xyt, tables, soa + 7 * stride, n);

        final_assemble<<<blocks, 256, 0, stream>>>(xyt, (const float2*)d_ws,
                                                   soa, out, n);
    } else if (d_ws != nullptr && ws_size >= DENSE_BYTES) {
        int bblocks = (OFFE[NDL] + 255) / 256;
        build_dense<<<bblocks, 256, 0, stream>>>(tables, (float2*)d_ws);
        hashgrid3d_dense<<<blocks, 256, 0, stream>>>(xyt, tables,
                                                     (const float2*)d_ws, out, n);
    } else {
        hashgrid3d_hash<<<blocks, 256, 0, stream>>>(xyt, tables, out, n);
    }
}